// Round 1
// baseline (1540.168 us; speedup 1.0000x reference)
//
#include <hip/hip_runtime.h>

// CrossShareUnit: B=8192, L=1, DL=DM=1024, K=8
// out order: [l_out | m_out | l_attn | m_attn], each 8192*1024 fp32.

#define NB 8192
#define DD 1024
#define NCOLS 9216   // 8192 (G cols, k*1024+e) + 1024 (Wc cols -> g_vec)

typedef __bf16 bf16x8 __attribute__((ext_vector_type(8)));
typedef float f32x4 __attribute__((ext_vector_type(4)));

__device__ __forceinline__ unsigned short f2bf(float f) {
  unsigned u = __float_as_uint(f);
  u += 0x7FFFu + ((u >> 16) & 1u);   // RNE to bf16
  return (unsigned short)(u >> 16);
}
__device__ __forceinline__ float bf2f(unsigned short h) {
  return __uint_as_float(((unsigned)h) << 16);
}

// ---- split fp32 -> bf16 hi + bf16 lo (row-major [NB x DD]) ----
__global__ __launch_bounds__(256) void split_cast_k(
    const float* __restrict__ in, unsigned short* __restrict__ hi,
    unsigned short* __restrict__ lo, int n4) {
  int i = blockIdx.x * 256 + threadIdx.x;
  if (i >= n4) return;
  float4 v = reinterpret_cast<const float4*>(in)[i];
  float vv[4] = {v.x, v.y, v.z, v.w};
  unsigned short hh[4], ll[4];
#pragma unroll
  for (int c = 0; c < 4; ++c) {
    hh[c] = f2bf(vv[c]);
    ll[c] = f2bf(vv[c] - bf2f(hh[c]));  // residual, exact in fp32
  }
  reinterpret_cast<ushort4*>(hi)[i] = make_ushort4(hh[0], hh[1], hh[2], hh[3]);
  reinterpret_cast<ushort4*>(lo)[i] = make_ushort4(ll[0], ll[1], ll[2], ll[3]);
}

// ---- transpose+split G [1024 x 8192] -> Bt rows 0..8191 ([col][d], K-contig) ----
__global__ __launch_bounds__(256) void transpose_split_k(
    const float* __restrict__ G, unsigned short* __restrict__ bhi,
    unsigned short* __restrict__ blo) {
  __shared__ float t[32][33];
  int c0 = blockIdx.x * 32;   // over 8192 cols
  int d0 = blockIdx.y * 32;   // over 1024 rows
  int tx = threadIdx.x & 31;
  int tg = threadIdx.x >> 5;  // 0..7
#pragma unroll
  for (int s = 0; s < 4; ++s) {
    int dr = tg * 4 + s;
    t[dr][tx] = G[(size_t)(d0 + dr) * 8192 + c0 + tx];
  }
  __syncthreads();
#pragma unroll
  for (int s = 0; s < 4; ++s) {
    int cr = tg * 4 + s;
    float v = t[tx][cr];                       // = G[d0+tx][c0+cr]
    size_t o = (size_t)(c0 + cr) * 1024 + d0 + tx;
    unsigned short h = f2bf(v);
    bhi[o] = h;
    blo[o] = f2bf(v - bf2f(h));
  }
}

// ---- Wc^T = (W2·W1)^T into Bt rows 8192..9215, plus bc = W2·b1 + b2 ----
__global__ __launch_bounds__(256) void wct_k(
    const float* __restrict__ w1, const float* __restrict__ b1,
    const float* __restrict__ w2, const float* __restrict__ b2, int J,
    unsigned short* __restrict__ bhi, unsigned short* __restrict__ blo,
    float* __restrict__ bc) {
  __shared__ float w2row[256];
  int n = blockIdx.x;          // 0..1023 output feature
  int tid = threadIdx.x;
  if (tid < J) w2row[tid] = w2[n * J + tid];
  __syncthreads();
#pragma unroll
  for (int s = 0; s < 4; ++s) {
    int i = tid + s * 256;     // input feature
    float acc = 0.f;
    for (int j = 0; j < J; ++j) acc = fmaf(w2row[j], w1[j * 1024 + i], acc);
    size_t o = (size_t)(8192 + n) * 1024 + i;
    unsigned short h = f2bf(acc);
    bhi[o] = h;
    blo[o] = f2bf(acc - bf2f(h));
  }
  if (tid == 0) {
    float acc = 0.f;
    for (int j = 0; j < J; ++j) acc = fmaf(w2row[j], b1[j], acc);
    bc[n] = acc + b2[n];
  }
}

// ---- main GEMM: C[b,n] = sum_k Astk[b,k]*Btstk[n,k], K=3072 (3 segs of 1024)
// segs: (Ahi,Bhi), (Alo,Bhi), (Ahi,Blo)  == (ahi+alo)(Ghi+Glo) - alo*Glo
// epilogue: n<8192 -> x[b, n>>10] += sum_e C*hb[b,e];  n>=8192 -> gvec store
__global__ __launch_bounds__(256) void gemm_k(
    const unsigned short* __restrict__ Ahi, const unsigned short* __restrict__ Alo,
    const unsigned short* __restrict__ Bhi, const unsigned short* __restrict__ Blo,
    const float* __restrict__ hb, float* __restrict__ gvec, float* __restrict__ x) {
  __shared__ __align__(16) unsigned short As[128 * 64];
  __shared__ __align__(16) unsigned short Bs[128 * 64];
  const int tid = threadIdx.x;
  const int lane = tid & 63;
  const int wid = tid >> 6;
  const int wm = wid >> 1, wn = wid & 1;
  const int m0 = blockIdx.y * 128;
  const int n0 = blockIdx.x * 128;

  f32x4 acc[4][4] = {};

  const int srow = wid * 8 + (lane >> 3);   // row within 32-row round chunk base
  const int skb = (lane & 7) * 16;          // byte offset within 128B k-row

  for (int kt = 0; kt < 48; ++kt) {
    const int seg = kt >> 4;
    const unsigned short* Ab = (seg == 1) ? Alo : Ahi;
    const unsigned short* Bb = (seg == 2) ? Blo : Bhi;
    const int kbyte0 = (kt & 15) * 128;     // 64 bf16 per tile
    __syncthreads();
#pragma unroll
    for (int r = 0; r < 4; ++r) {
      const char* asrc = (const char*)Ab + (size_t)(m0 + r * 32 + srow) * 2048 + kbyte0 + skb;
      const char* bsrc = (const char*)Bb + (size_t)(n0 + r * 32 + srow) * 2048 + kbyte0 + skb;
      char* adst = (char*)As + r * 4096 + wid * 1024;   // wave-uniform base
      char* bdst = (char*)Bs + r * 4096 + wid * 1024;
      __builtin_amdgcn_global_load_lds(
          (const __attribute__((address_space(1))) void*)asrc,
          (__attribute__((address_space(3))) void*)adst, 16, 0, 0);
      __builtin_amdgcn_global_load_lds(
          (const __attribute__((address_space(1))) void*)bsrc,
          (__attribute__((address_space(3))) void*)bdst, 16, 0, 0);
    }
    __syncthreads();
#pragma unroll
    for (int ks = 0; ks < 2; ++ks) {
      bf16x8 af[4], bfr[4];
#pragma unroll
      for (int f = 0; f < 4; ++f) {
        int arow = wm * 64 + f * 16 + (lane & 15);
        af[f] = *reinterpret_cast<const bf16x8*>(&As[arow * 64 + ks * 32 + (lane >> 4) * 8]);
        int brow = wn * 64 + f * 16 + (lane & 15);
        bfr[f] = *reinterpret_cast<const bf16x8*>(&Bs[brow * 64 + ks * 32 + (lane >> 4) * 8]);
      }
#pragma unroll
      for (int i = 0; i < 4; ++i)
#pragma unroll
        for (int j = 0; j < 4; ++j)
          acc[i][j] = __builtin_amdgcn_mfma_f32_16x16x32_bf16(af[i], bfr[j], acc[i][j], 0, 0, 0);
    }
  }

  const int coll = lane & 15;
  const int rgrp = (lane >> 4) * 4;
  if (n0 >= 8192) {
    // g_vec region: each element written exactly once
#pragma unroll
    for (int i = 0; i < 4; ++i)
#pragma unroll
      for (int r = 0; r < 4; ++r) {
        int row = m0 + wm * 64 + i * 16 + rgrp + r;
#pragma unroll
        for (int j = 0; j < 4; ++j) {
          int gcol = (n0 - 8192) + wn * 64 + j * 16 + coll;
          gvec[(size_t)row * 1024 + gcol] = acc[i][j][r];
        }
      }
  } else {
    const int kidx = n0 >> 10;
    const int ebase = (n0 & 1023) + wn * 64 + coll;
#pragma unroll
    for (int i = 0; i < 4; ++i)
#pragma unroll
      for (int r = 0; r < 4; ++r) {
        int row = m0 + wm * 64 + i * 16 + rgrp + r;
        const float* hr = hb + (size_t)row * 1024 + ebase;
        float tmp = acc[i][0][r] * hr[0] + acc[i][1][r] * hr[16] +
                    acc[i][2][r] * hr[32] + acc[i][3][r] * hr[48];
#pragma unroll
        for (int s = 1; s < 16; s <<= 1) tmp += __shfl_xor(tmp, s);
        if (coll == 0) atomicAdd(&x[row * 8 + kidx], tmp);
      }
  }
}

// ---- per-batch: S = sum tanh(x), vec = S*(gvec+bc), softmax, out/attn ----
__global__ __launch_bounds__(256) void finalize_k(
    const float* __restrict__ xk, const float* __restrict__ gvec,
    const float* __restrict__ bc, const float* __restrict__ ha,
    float* __restrict__ out, float* __restrict__ attn) {
  int b = blockIdx.x;
  int tid = threadIdx.x;
  float S = 0.f;
#pragma unroll
  for (int k = 0; k < 8; ++k) S += tanhf(xk[b * 8 + k]);
  float v[4];
  float mx = -3.4e38f;
#pragma unroll
  for (int s = 0; s < 4; ++s) {
    int d = tid + s * 256;
    v[s] = S * (gvec[(size_t)b * 1024 + d] + bc[d]);
    mx = fmaxf(mx, v[s]);
  }
  __shared__ float red[8];
#pragma unroll
  for (int off = 32; off >= 1; off >>= 1) mx = fmaxf(mx, __shfl_xor(mx, off));
  int lane = tid & 63, w = tid >> 6;
  if (lane == 0) red[w] = mx;
  __syncthreads();
  float m = fmaxf(fmaxf(red[0], red[1]), fmaxf(red[2], red[3]));
  float e[4], sum = 0.f;
#pragma unroll
  for (int s = 0; s < 4; ++s) { e[s] = __expf(v[s] - m); sum += e[s]; }
#pragma unroll
  for (int off = 32; off >= 1; off >>= 1) sum += __shfl_xor(sum, off);
  if (lane == 0) red[4 + w] = sum;
  __syncthreads();
  float inv = 1.f / (red[4] + red[5] + red[6] + red[7]);
#pragma unroll
  for (int s = 0; s < 4; ++s) {
    int d = tid + s * 256;
    float a = e[s] * inv;
    attn[(size_t)b * 1024 + d] = a;
    float h = ha[(size_t)b * 1024 + d];
    out[(size_t)b * 1024 + d] = fmaf(a, h, h);
  }
}

extern "C" void kernel_launch(void* const* d_in, const int* in_sizes, int n_in,
                              void* d_out, int out_size, void* d_ws, size_t ws_size,
                              hipStream_t stream) {
  const float* l_hidden = (const float*)d_in[0];
  const float* m_hidden = (const float*)d_in[1];
  const float* G_l_m = (const float*)d_in[2];
  const float* G_m_l = (const float*)d_in[3];
  const float* l_fc1_w = (const float*)d_in[4];
  const float* l_fc1_b = (const float*)d_in[5];
  const float* l_fc2_w = (const float*)d_in[6];
  const float* l_fc2_b = (const float*)d_in[7];
  const float* m_fc1_w = (const float*)d_in[8];
  const float* m_fc1_b = (const float*)d_in[9];
  const float* m_fc2_w = (const float*)d_in[10];
  const float* m_fc2_b = (const float*)d_in[11];
  float* out = (float*)d_out;

  // ws layout (bytes): ~101 MB total
  char* ws = (char*)d_ws;
  unsigned short* Ahi = (unsigned short*)(ws);                    // 16 MB
  unsigned short* Alo = (unsigned short*)(ws + 16777216);         // 16 MB
  unsigned short* Bhi = (unsigned short*)(ws + 33554432);         // 18 MB (9216x1024)
  unsigned short* Blo = (unsigned short*)(ws + 52428800);         // 18 MB
  float* gvec = (float*)(ws + 71303168);                          // 32 MB (one dir at a time)
  float* x = (float*)(ws + 104857600);                            // 512 KB (2 dirs)
  float* bc = (float*)(ws + 105381888);                           // 4 KB (reused per dir)

  hipMemsetAsync(x, 0, 2 * NB * 8 * sizeof(float), stream);

  const size_t BD = (size_t)NB * DD;
  dim3 gemmGrid(72, 64);

  // direction l: x_l[b,k] = h_l^T G_lm,k h_m ; g_vec from l-FCs
  split_cast_k<<<(int)(BD / 4 / 256), 256, 0, stream>>>(l_hidden, Ahi, Alo, (int)(BD / 4));
  transpose_split_k<<<dim3(256, 32), 256, 0, stream>>>(G_l_m, Bhi, Blo);
  wct_k<<<1024, 256, 0, stream>>>(l_fc1_w, l_fc1_b, l_fc2_w, l_fc2_b, 256, Bhi, Blo, bc);
  gemm_k<<<gemmGrid, 256, 0, stream>>>(Ahi, Alo, Bhi, Blo, m_hidden, gvec, x);
  finalize_k<<<NB, 256, 0, stream>>>(x, gvec, bc, l_hidden, out, out + 2 * BD);

  // direction m (buffers reused; stream order serializes)
  split_cast_k<<<(int)(BD / 4 / 256), 256, 0, stream>>>(m_hidden, Ahi, Alo, (int)(BD / 4));
  transpose_split_k<<<dim3(256, 32), 256, 0, stream>>>(G_m_l, Bhi, Blo);
  wct_k<<<1024, 256, 0, stream>>>(m_fc1_w, m_fc1_b, m_fc2_w, m_fc2_b, 128, Bhi, Blo, bc);
  gemm_k<<<gemmGrid, 256, 0, stream>>>(Ahi, Alo, Bhi, Blo, l_hidden, gvec, x + NB * 8);
  finalize_k<<<NB, 256, 0, stream>>>(x + NB * 8, gvec, bc, m_hidden, out + BD, out + 3 * BD);
}

// Round 2
// 1244.060 us; speedup vs baseline: 1.2380x; 1.2380x over previous
//
#include <hip/hip_runtime.h>

// CrossShareUnit: B=8192, L=1, DL=DM=1024, K=8
// out order: [l_out | m_out | l_attn | m_attn], each 8192*1024 fp32.

#define NB 8192
#define DD 1024

typedef __bf16 bf16x8 __attribute__((ext_vector_type(8)));
typedef float f32x4 __attribute__((ext_vector_type(4)));

__device__ __forceinline__ unsigned short f2bf(float f) {
  unsigned u = __float_as_uint(f);
  u += 0x7FFFu + ((u >> 16) & 1u);   // RNE to bf16
  return (unsigned short)(u >> 16);
}
__device__ __forceinline__ float bf2f(unsigned short h) {
  return __uint_as_float(((unsigned)h) << 16);
}

// ---- split fp32 -> bf16 hi + bf16 lo (row-major [NB x DD]) ----
__global__ __launch_bounds__(256) void split_cast_k(
    const float* __restrict__ in, unsigned short* __restrict__ hi,
    unsigned short* __restrict__ lo, int n4) {
  int i = blockIdx.x * 256 + threadIdx.x;
  if (i >= n4) return;
  float4 v = reinterpret_cast<const float4*>(in)[i];
  float vv[4] = {v.x, v.y, v.z, v.w};
  unsigned short hh[4], ll[4];
#pragma unroll
  for (int c = 0; c < 4; ++c) {
    hh[c] = f2bf(vv[c]);
    ll[c] = f2bf(vv[c] - bf2f(hh[c]));
  }
  reinterpret_cast<ushort4*>(hi)[i] = make_ushort4(hh[0], hh[1], hh[2], hh[3]);
  reinterpret_cast<ushort4*>(lo)[i] = make_ushort4(ll[0], ll[1], ll[2], ll[3]);
}

// ---- transpose+split G [1024 x 8192] -> Bt rows 0..8191 ([col][d]) ----
__global__ __launch_bounds__(256) void transpose_split_k(
    const float* __restrict__ G, unsigned short* __restrict__ bhi,
    unsigned short* __restrict__ blo) {
  __shared__ float t[32][33];
  int c0 = blockIdx.x * 32;
  int d0 = blockIdx.y * 32;
  int tx = threadIdx.x & 31;
  int tg = threadIdx.x >> 5;
#pragma unroll
  for (int s = 0; s < 4; ++s) {
    int dr = tg * 4 + s;
    t[dr][tx] = G[(size_t)(d0 + dr) * 8192 + c0 + tx];
  }
  __syncthreads();
#pragma unroll
  for (int s = 0; s < 4; ++s) {
    int cr = tg * 4 + s;
    float v = t[tx][cr];
    size_t o = (size_t)(c0 + cr) * 1024 + d0 + tx;
    unsigned short h = f2bf(v);
    bhi[o] = h;
    blo[o] = f2bf(v - bf2f(h));
  }
}

// ---- Wc^T = (W2·W1)^T into Bt rows 8192..9215, plus bc = W2·b1 + b2 ----
__global__ __launch_bounds__(256) void wct_k(
    const float* __restrict__ w1, const float* __restrict__ b1,
    const float* __restrict__ w2, const float* __restrict__ b2, int J,
    unsigned short* __restrict__ bhi, unsigned short* __restrict__ blo,
    float* __restrict__ bc) {
  __shared__ float w2row[256];
  int n = blockIdx.x;
  int tid = threadIdx.x;
  if (tid < J) w2row[tid] = w2[n * J + tid];
  __syncthreads();
#pragma unroll
  for (int s = 0; s < 4; ++s) {
    int i = tid + s * 256;
    float acc = 0.f;
    for (int j = 0; j < J; ++j) acc = fmaf(w2row[j], w1[j * 1024 + i], acc);
    size_t o = (size_t)(8192 + n) * 1024 + i;
    unsigned short h = f2bf(acc);
    bhi[o] = h;
    blo[o] = f2bf(acc - bf2f(h));
  }
  if (tid == 0) {
    float acc = 0.f;
    for (int j = 0; j < J; ++j) acc = fmaf(w2row[j], b1[j], acc);
    bc[n] = acc + b2[n];
  }
}

// ============================================================================
// 256x256 8-phase GEMM (T1+T2+T3/T4+T5).  C[b,n] = sum_k Aseg[b,k]*Bseg[n,k]
// K=3072 as 3 segments of 1024: (Ahi,Bhi),(Alo,Bhi),(Ahi,Blo).
// LDS: A dbuf 2x256x64bf16 (64KB) | B dbuf (64KB) | dummy sink (16KB) = 144KB.
// Per K-tile (BK=64): 4 phases; stages flow h = 4t+5..4t+8 (tile t+1 q1..q3,
// tile t+2 q0); counted s_waitcnt vmcnt(2) once per tile (never 0).
// Swizzle: LDS dest linear; global SOURCE col-slot ^= (row&7); ds_read slot
// ^= (row&7).  row&7 == lane&7 on read side, == (tid>>3)&7 on stage side.
// ============================================================================
#define SBAR() do { asm volatile("" ::: "memory"); __builtin_amdgcn_s_barrier(); asm volatile("" ::: "memory"); } while (0)
#define WAITV2() asm volatile("s_waitcnt vmcnt(2)" ::: "memory")

__global__ __launch_bounds__(512, 2) void gemm_k(
    const unsigned short* __restrict__ Ahi_, const unsigned short* __restrict__ Alo_,
    const unsigned short* __restrict__ Bhi_, const unsigned short* __restrict__ Blo_,
    const float* __restrict__ hb, float* __restrict__ gvec, float* __restrict__ x) {
  __shared__ __align__(16) char lds[147456];
  const char* Ah = (const char*)Ahi_;
  const char* Al = (const char*)Alo_;
  const char* Bh = (const char*)Bhi_;
  const char* Bl = (const char*)Blo_;

  const int tid = threadIdx.x;
  const int lane = tid & 63;
  const int wid = tid >> 6;
  const int wm = wid >> 2, wn = wid & 3;

  // bijective XCD swizzle: 1152 blocks = 8 chunks x 144; M-major inside chunk
  const int bid = blockIdx.x;
  const int wg = (bid & 7) * 144 + (bid >> 3);
  const int by = wg & 31;         // 32 M-tiles
  const int bx = wg >> 5;         // 36 N-tiles
  const int m0 = by * 256, n0 = bx * 256;
  const int nt = (n0 >= 8192) ? 16 : 48;  // gvec blocks: hi*hi segment only
  const int nt4 = nt * 4;

  // staging constants (source pre-swizzle)
  const int rowl = tid >> 3;                              // 0..63 row / round
  const int colsw = ((tid & 7) ^ ((tid >> 3) & 7)) << 4;  // swizzled 16B slot
  // read constants
  const int rowb = (lane & 15) << 7;
  const int s0 = ((lane >> 4) ^ (lane & 7)) << 4;  // ks=0 slot byte
  const int s1 = s0 ^ 64;                          // ks=1

  f32x4 acc[8][4] = {};

#define GLOAD(SRC, DST)                                              \
  __builtin_amdgcn_global_load_lds(                                  \
      (const __attribute__((address_space(1))) void*)(SRC),          \
      (__attribute__((address_space(3))) void*)(lds + (DST)), 16, 0, 0)

  auto stage = [&](int h) {
    const char* src;
    int dst;
    if (h < nt4) {
      const int th = h >> 2, q = h & 3, seg = th >> 4;
      const char* mat;
      int rowoff;
      if (q < 2) {
        mat = (seg == 1) ? Al : Ah;
        rowoff = m0 + (q & 1) * 128;
        dst = (th & 1) * 32768 + (q & 1) * 16384;
      } else {
        mat = (seg == 2) ? Bl : Bh;
        rowoff = n0 + (q & 1) * 128;
        dst = 65536 + (th & 1) * 32768 + (q & 1) * 16384;
      }
      src = mat + (size_t)(rowoff + rowl) * 2048 + ((th & 15) << 7) + colsw;
    } else {  // dummy sink: keeps per-thread vmcnt bookkeeping uniform
      src = Ah + (size_t)(m0 + rowl) * 2048 + colsw;
      dst = 131072;
    }
    dst += wid * 1024;
    GLOAD(src, dst);                     // rows r .. (round 0)
    GLOAD(src + 64 * 2048, dst + 8192);  // rows r+64 (round 1)
  };

  auto ldA = [&](bf16x8 (*d)[2], int msub, int cb) {
#pragma unroll
    for (int f = 0; f < 4; ++f) {
      const char* p = lds + cb + wm * 16384 + msub * 8192 + f * 2048 + rowb;
      d[f][0] = *reinterpret_cast<const bf16x8*>(p + s0);
      d[f][1] = *reinterpret_cast<const bf16x8*>(p + s1);
    }
  };
  auto ldB = [&](bf16x8 (*d)[2], int nsub, int cb) {
#pragma unroll
    for (int g = 0; g < 2; ++g) {
      const char* p = lds + 65536 + cb + wn * 8192 + (nsub * 2 + g) * 2048 + rowb;
      d[g][0] = *reinterpret_cast<const bf16x8*>(p + s0);
      d[g][1] = *reinterpret_cast<const bf16x8*>(p + s1);
    }
  };
  auto mm = [&](int iof, bf16x8 (*aa)[2], int jof, bf16x8 (*bb)[2]) {
#pragma unroll
    for (int f = 0; f < 4; ++f)
#pragma unroll
      for (int g = 0; g < 2; ++g) {
        acc[iof + f][jof + g] = __builtin_amdgcn_mfma_f32_16x16x32_bf16(
            aa[f][0], bb[g][0], acc[iof + f][jof + g], 0, 0, 0);
        acc[iof + f][jof + g] = __builtin_amdgcn_mfma_f32_16x16x32_bf16(
            aa[f][1], bb[g][1], acc[iof + f][jof + g], 0, 0, 0);
      }
  };

  // prologue: tile0 q0-3 + tile1 q0; wait all but newest half
  for (int h = 0; h < 5; ++h) stage(h);
  WAITV2();
  SBAR();

  for (int t = 0; t < nt; ++t) {
    const int cb = (t & 1) * 32768;
    bf16x8 af0[4][2], af1[4][2], b0[2][2], b1[2][2];

    // ---- phase 0: A msub0 + B nsub0; MFMA (m0, n0..1)
    ldA(af0, 0, cb);
    ldB(b0, 0, cb);
    stage(4 * t + 5);
    SBAR();
    __builtin_amdgcn_s_setprio(1);
    mm(0, af0, 0, b0);
    __builtin_amdgcn_s_setprio(0);
    SBAR();
    // ---- phase 1: B nsub1; MFMA (m0, n2..3)
    ldB(b1, 1, cb);
    stage(4 * t + 6);
    SBAR();
    __builtin_amdgcn_s_setprio(1);
    mm(0, af0, 2, b1);
    __builtin_amdgcn_s_setprio(0);
    SBAR();
    // ---- phase 2: A msub1; MFMA (m1, n0..1)
    ldA(af1, 1, cb);
    stage(4 * t + 7);
    SBAR();
    __builtin_amdgcn_s_setprio(1);
    mm(4, af1, 0, b0);
    __builtin_amdgcn_s_setprio(0);
    SBAR();
    // ---- phase 3: counted vmcnt (next tile landed, newest half in flight)
    stage(4 * t + 8);
    WAITV2();
    SBAR();
    __builtin_amdgcn_s_setprio(1);
    mm(4, af1, 2, b1);
    __builtin_amdgcn_s_setprio(0);
    SBAR();
  }

  // ---- epilogue (no LDS use) ----
  const int coll = lane & 15;
  const int rg = (lane >> 4) * 4;
  if (n0 >= 8192) {
#pragma unroll
    for (int i = 0; i < 8; ++i)
#pragma unroll
      for (int r = 0; r < 4; ++r) {
        const int row = m0 + wm * 128 + i * 16 + rg + r;
#pragma unroll
        for (int j = 0; j < 4; ++j) {
          const int gcol = (n0 - 8192) + wn * 64 + j * 16 + coll;
          gvec[(size_t)row * 1024 + gcol] = acc[i][j][r];
        }
      }
  } else {
    const int kidx = n0 >> 10;
    const int ebase = (n0 & 1023) + wn * 64 + coll;
#pragma unroll
    for (int i = 0; i < 8; ++i)
#pragma unroll
      for (int r = 0; r < 4; ++r) {
        const int row = m0 + wm * 128 + i * 16 + rg + r;
        const float* hr = hb + (size_t)row * 1024 + ebase;
        float tmp = acc[i][0][r] * hr[0] + acc[i][1][r] * hr[16] +
                    acc[i][2][r] * hr[32] + acc[i][3][r] * hr[48];
#pragma unroll
        for (int s = 1; s < 16; s <<= 1) tmp += __shfl_xor(tmp, s);
        if (coll == 0) atomicAdd(&x[row * 8 + kidx], tmp);
      }
  }
}

// ---- per-batch: S = sum tanh(x), vec = S*(gvec+bc), softmax, out/attn ----
__global__ __launch_bounds__(256) void finalize_k(
    const float* __restrict__ xk, const float* __restrict__ gvec,
    const float* __restrict__ bc, const float* __restrict__ ha,
    float* __restrict__ out, float* __restrict__ attn) {
  int b = blockIdx.x;
  int tid = threadIdx.x;
  float S = 0.f;
#pragma unroll
  for (int k = 0; k < 8; ++k) S += tanhf(xk[b * 8 + k]);
  float v[4];
  float mx = -3.4e38f;
#pragma unroll
  for (int s = 0; s < 4; ++s) {
    int d = tid + s * 256;
    v[s] = S * (gvec[(size_t)b * 1024 + d] + bc[d]);
    mx = fmaxf(mx, v[s]);
  }
  __shared__ float red[8];
#pragma unroll
  for (int off = 32; off >= 1; off >>= 1) mx = fmaxf(mx, __shfl_xor(mx, off));
  int lane = tid & 63, w = tid >> 6;
  if (lane == 0) red[w] = mx;
  __syncthreads();
  float m = fmaxf(fmaxf(red[0], red[1]), fmaxf(red[2], red[3]));
  float e[4], sum = 0.f;
#pragma unroll
  for (int s = 0; s < 4; ++s) { e[s] = __expf(v[s] - m); sum += e[s]; }
#pragma unroll
  for (int off = 32; off >= 1; off >>= 1) sum += __shfl_xor(sum, off);
  if (lane == 0) red[4 + w] = sum;
  __syncthreads();
  float inv = 1.f / (red[4] + red[5] + red[6] + red[7]);
#pragma unroll
  for (int s = 0; s < 4; ++s) {
    int d = tid + s * 256;
    float a = e[s] * inv;
    attn[(size_t)b * 1024 + d] = a;
    float h = ha[(size_t)b * 1024 + d];
    out[(size_t)b * 1024 + d] = fmaf(a, h, h);
  }
}

extern "C" void kernel_launch(void* const* d_in, const int* in_sizes, int n_in,
                              void* d_out, int out_size, void* d_ws, size_t ws_size,
                              hipStream_t stream) {
  const float* l_hidden = (const float*)d_in[0];
  const float* m_hidden = (const float*)d_in[1];
  const float* G_l_m = (const float*)d_in[2];
  const float* G_m_l = (const float*)d_in[3];
  const float* l_fc1_w = (const float*)d_in[4];
  const float* l_fc1_b = (const float*)d_in[5];
  const float* l_fc2_w = (const float*)d_in[6];
  const float* l_fc2_b = (const float*)d_in[7];
  const float* m_fc1_w = (const float*)d_in[8];
  const float* m_fc1_b = (const float*)d_in[9];
  const float* m_fc2_w = (const float*)d_in[10];
  const float* m_fc2_b = (const float*)d_in[11];
  float* out = (float*)d_out;

  char* ws = (char*)d_ws;
  unsigned short* Ahi = (unsigned short*)(ws);                    // 16 MB
  unsigned short* Alo = (unsigned short*)(ws + 16777216);         // 16 MB
  unsigned short* Bhi = (unsigned short*)(ws + 33554432);         // 18 MB (9216x1024)
  unsigned short* Blo = (unsigned short*)(ws + 52428800);         // 18 MB
  float* gvec = (float*)(ws + 71303168);                          // 32 MB
  float* x = (float*)(ws + 104857600);                            // 512 KB (2 dirs)
  float* bc = (float*)(ws + 105381888);                           // 4 KB

  hipMemsetAsync(x, 0, 2 * NB * 8 * sizeof(float), stream);

  const size_t BD = (size_t)NB * DD;
  dim3 gemmGrid(1152);

  // direction l
  split_cast_k<<<(int)(BD / 4 / 256), 256, 0, stream>>>(l_hidden, Ahi, Alo, (int)(BD / 4));
  transpose_split_k<<<dim3(256, 32), 256, 0, stream>>>(G_l_m, Bhi, Blo);
  wct_k<<<1024, 256, 0, stream>>>(l_fc1_w, l_fc1_b, l_fc2_w, l_fc2_b, 256, Bhi, Blo, bc);
  gemm_k<<<gemmGrid, 512, 0, stream>>>(Ahi, Alo, Bhi, Blo, m_hidden, gvec, x);
  finalize_k<<<NB, 256, 0, stream>>>(x, gvec, bc, l_hidden, out, out + 2 * BD);

  // direction m
  split_cast_k<<<(int)(BD / 4 / 256), 256, 0, stream>>>(m_hidden, Ahi, Alo, (int)(BD / 4));
  transpose_split_k<<<dim3(256, 32), 256, 0, stream>>>(G_m_l, Bhi, Blo);
  wct_k<<<1024, 256, 0, stream>>>(m_fc1_w, m_fc1_b, m_fc2_w, m_fc2_b, 128, Bhi, Blo, bc);
  gemm_k<<<gemmGrid, 512, 0, stream>>>(Ahi, Alo, Bhi, Blo, l_hidden, gvec, x + NB * 8);
  finalize_k<<<NB, 256, 0, stream>>>(x + NB * 8, gvec, bc, m_hidden, out + BD, out + 3 * BD);
}

// Round 3
// 1094.815 us; speedup vs baseline: 1.4068x; 1.1363x over previous
//
#include <hip/hip_runtime.h>

// CrossShareUnit: B=8192, L=1, DL=DM=1024, K=8
// out order: [l_out | m_out | l_attn | m_attn], each 8192*1024 fp32.

#define NB 8192
#define DD 1024

typedef __bf16 bf16x8 __attribute__((ext_vector_type(8)));
typedef float f32x4 __attribute__((ext_vector_type(4)));

__device__ __forceinline__ unsigned short f2bf(float f) {
  unsigned u = __float_as_uint(f);
  u += 0x7FFFu + ((u >> 16) & 1u);   // RNE to bf16
  return (unsigned short)(u >> 16);
}
__device__ __forceinline__ float bf2f(unsigned short h) {
  return __uint_as_float(((unsigned)h) << 16);
}

// ---- split fp32 -> bf16 hi + bf16 lo (row-major [NB x DD]) ----
__global__ __launch_bounds__(256) void split_cast_k(
    const float* __restrict__ in, unsigned short* __restrict__ hi,
    unsigned short* __restrict__ lo, int n4) {
  int i = blockIdx.x * 256 + threadIdx.x;
  if (i >= n4) return;
  float4 v = reinterpret_cast<const float4*>(in)[i];
  float vv[4] = {v.x, v.y, v.z, v.w};
  unsigned short hh[4], ll[4];
#pragma unroll
  for (int c = 0; c < 4; ++c) {
    hh[c] = f2bf(vv[c]);
    ll[c] = f2bf(vv[c] - bf2f(hh[c]));
  }
  reinterpret_cast<ushort4*>(hi)[i] = make_ushort4(hh[0], hh[1], hh[2], hh[3]);
  reinterpret_cast<ushort4*>(lo)[i] = make_ushort4(ll[0], ll[1], ll[2], ll[3]);
}

// ---- transpose+split G [1024 x 8192] -> Bt rows 0..8191 ([col][d]) ----
__global__ __launch_bounds__(256) void transpose_split_k(
    const float* __restrict__ G, unsigned short* __restrict__ bhi,
    unsigned short* __restrict__ blo) {
  __shared__ float t[32][33];
  int c0 = blockIdx.x * 32;
  int d0 = blockIdx.y * 32;
  int tx = threadIdx.x & 31;
  int tg = threadIdx.x >> 5;
#pragma unroll
  for (int s = 0; s < 4; ++s) {
    int dr = tg * 4 + s;
    t[dr][tx] = G[(size_t)(d0 + dr) * 8192 + c0 + tx];
  }
  __syncthreads();
#pragma unroll
  for (int s = 0; s < 4; ++s) {
    int cr = tg * 4 + s;
    float v = t[tx][cr];
    size_t o = (size_t)(c0 + cr) * 1024 + d0 + tx;
    unsigned short h = f2bf(v);
    bhi[o] = h;
    blo[o] = f2bf(v - bf2f(h));
  }
}

// ---- Wc^T = (W2·W1)^T into Bt rows 8192..9215, plus bc = W2·b1 + b2 ----
__global__ __launch_bounds__(256) void wct_k(
    const float* __restrict__ w1, const float* __restrict__ b1,
    const float* __restrict__ w2, const float* __restrict__ b2, int J,
    unsigned short* __restrict__ bhi, unsigned short* __restrict__ blo,
    float* __restrict__ bc) {
  __shared__ float w2row[256];
  int n = blockIdx.x;
  int tid = threadIdx.x;
  if (tid < J) w2row[tid] = w2[n * J + tid];
  __syncthreads();
#pragma unroll
  for (int s = 0; s < 4; ++s) {
    int i = tid + s * 256;
    float acc = 0.f;
    for (int j = 0; j < J; ++j) acc = fmaf(w2row[j], w1[j * 1024 + i], acc);
    size_t o = (size_t)(8192 + n) * 1024 + i;
    unsigned short h = f2bf(acc);
    bhi[o] = h;
    blo[o] = f2bf(acc - bf2f(h));
  }
  if (tid == 0) {
    float acc = 0.f;
    for (int j = 0; j < J; ++j) acc = fmaf(w2row[j], b1[j], acc);
    bc[n] = acc + b2[n];
  }
}

// ============================================================================
// 256x256 quadrant-phased GEMM.  C[b,n] = sum_k Aseg[b,k]*Bseg[n,k]
// K=3072 as 3 segments of 1024: (Ahi,Bhi),(Alo,Bhi),(Ahi,Blo).
// Phase p of tile t computes C-quadrant: ph0=(0,0) ph1=(0,1) ph2=(1,1)
// ph3=(1,0); each phase reads exactly ONE A-quarter + ONE B-quarter.
// Stage schedule (tile t): ph0 -> (t+1,A0)+(t+1,B0); ph1 -> (t+1,B1);
// ph2 -> (t+1,A1); ph3 -> none.  Waits: ph0 vmcnt(6) [drain (t,B1)],
// ph1 vmcnt(6) [drain (t,A1)], ph3 vmcnt(4) [drain (t+1,A0B0)].
// Every load has >=3 phases issue-to-wait cover; never drains below 4.
// LDS: A dbuf 2x(2 quarters x 16KB) | B same | sink 16KB = 144KB.
// Swizzle: LDS linear (gload_lds), global SOURCE slot ^= row&7, ds_read
// slot ^= row&7 (rule #21 both-sides).
// ============================================================================
#define SBAR() do { asm volatile("" ::: "memory"); __builtin_amdgcn_s_barrier(); asm volatile("" ::: "memory"); } while (0)
#define WAITV4() asm volatile("s_waitcnt vmcnt(4)" ::: "memory")
#define WAITV6() asm volatile("s_waitcnt vmcnt(6)" ::: "memory")

#define GLOAD(SRC, DST)                                              \
  __builtin_amdgcn_global_load_lds(                                  \
      (const __attribute__((address_space(1))) void*)(SRC),          \
      (__attribute__((address_space(3))) void*)(lds + (DST)), 16, 0, 0)

__global__ __launch_bounds__(512, 2) void gemm_k(
    const unsigned short* __restrict__ Ahi_, const unsigned short* __restrict__ Alo_,
    const unsigned short* __restrict__ Bhi_, const unsigned short* __restrict__ Blo_,
    const float* __restrict__ hb, float* __restrict__ gvec, float* __restrict__ x) {
  __shared__ __align__(16) char lds[147456];
  const char* Ah = (const char*)Ahi_;
  const char* Al = (const char*)Alo_;
  const char* Bh = (const char*)Bhi_;
  const char* Bl = (const char*)Blo_;

  const int tid = threadIdx.x;
  const int lane = tid & 63;
  const int wid = tid >> 6;
  const int wm = wid >> 2, wn = wid & 3;   // wave covers 64x32 of each quadrant

  // XCD-aware: each XCD owns a 4-row M-band (A panels stay L2-resident);
  // by-inner so 4 concurrent blocks share each B panel; gvec tiles last.
  const int bid = blockIdx.x;
  const int xcd = bid & 7, j = bid >> 3;   // j 0..143
  const int by = xcd * 4 + (j & 3);        // 0..31
  const int bx = j >> 2;                   // 0..35
  const int m0 = by * 256, n0 = bx * 256;
  const int nt = (n0 >= 8192) ? 16 : 48;   // gvec tiles: hi*hi only

  const int rowl = tid >> 3;                               // staged row 0..63
  const int colsw = ((tid & 7) ^ ((tid >> 3) & 7)) << 4;   // pre-swizzled src slot
  const int s0 = ((lane >> 4) ^ (lane & 7)) << 4;          // ds_read slot ks=0
  const int s1 = s0 ^ 64;                                  // ks=1

  f32x4 acc[4][4][2] = {};   // [quadrant 0:(00) 1:(01) 2:(11) 3:(10)][f][g]

  // q: 0=A rows 0..127, 1=A rows 128..255, 2=B rows 0..127, 3=B rows 128..255
  auto stage = [&](int tile, int q) {
    if (tile < nt) {
      const int seg = tile >> 4;
      const char* mat;
      int rowbase, dst;
      if (q < 2) {
        mat = (seg == 1) ? Al : Ah;
        rowbase = m0 + q * 128;
        dst = (tile & 1) * 32768 + q * 16384;
      } else {
        mat = (seg == 2) ? Bl : Bh;
        rowbase = n0 + (q - 2) * 128;
        dst = 65536 + (tile & 1) * 32768 + (q - 2) * 16384;
      }
      const char* src = mat + (size_t)(rowbase + rowl) * 2048 + ((tile & 15) << 7) + colsw;
      dst += wid * 1024;                    // wave-uniform LDS base
      GLOAD(src, dst);                      // rows 0..63 of quarter
      GLOAD(src + 64 * 2048, dst + 8192);   // rows 64..127
    } else {  // dummy sink keeps per-wave vmcnt bookkeeping uniform
      const char* src = Ah + (size_t)(m0 + rowl) * 2048 + colsw;
      const int d2 = 131072 + wid * 1024;
      GLOAD(src, d2);
      GLOAD(src + 64 * 2048, d2 + 8192);
    }
  };

  auto ldA = [&](bf16x8 (*d)[2], int qa, int cb) {
    const char* p = lds + cb + qa * 16384 + (wm * 64 + (lane & 15)) * 128;
#pragma unroll
    for (int f = 0; f < 4; ++f) {
      d[f][0] = *reinterpret_cast<const bf16x8*>(p + f * 2048 + s0);
      d[f][1] = *reinterpret_cast<const bf16x8*>(p + f * 2048 + s1);
    }
  };
  auto ldB = [&](bf16x8 (*d)[2], int qb, int cb) {
    const char* p = lds + 65536 + cb + qb * 16384 + (wn * 32 + (lane & 15)) * 128;
#pragma unroll
    for (int g = 0; g < 2; ++g) {
      d[g][0] = *reinterpret_cast<const bf16x8*>(p + g * 2048 + s0);
      d[g][1] = *reinterpret_cast<const bf16x8*>(p + g * 2048 + s1);
    }
  };
  auto mm = [&](f32x4 (*ac)[2], bf16x8 (*aa)[2], bf16x8 (*bb)[2]) {
#pragma unroll
    for (int f = 0; f < 4; ++f)
#pragma unroll
      for (int g = 0; g < 2; ++g) {
        ac[f][g] = __builtin_amdgcn_mfma_f32_16x16x32_bf16(aa[f][0], bb[g][0], ac[f][g], 0, 0, 0);
        ac[f][g] = __builtin_amdgcn_mfma_f32_16x16x32_bf16(aa[f][1], bb[g][1], ac[f][g], 0, 0, 0);
      }
  };

  // prologue: tile0 in issue order A0,B0 | B1 | A1; drain A0,B0
  stage(0, 0); stage(0, 2);
  stage(0, 3);
  stage(0, 1);
  WAITV4();
  SBAR();

  bf16x8 af[4][2], af2[4][2], bv[2][2], bv2[2][2];
  for (int t = 0; t < nt; ++t) {
    const int cb = (t & 1) * 32768;
    // ph0: quadrant (0,0) — reads A0,B0
    ldA(af, 0, cb);
    ldB(bv, 0, cb);
    stage(t + 1, 0); stage(t + 1, 2);
    SBAR();
    __builtin_amdgcn_s_setprio(1);
    mm(acc[0], af, bv);
    __builtin_amdgcn_s_setprio(0);
    WAITV6();            // drain (t,B1) — issued 3 phases ago
    SBAR();
    // ph1: quadrant (0,1) — reads B1 (reuses af)
    ldB(bv2, 1, cb);
    stage(t + 1, 3);
    SBAR();
    __builtin_amdgcn_s_setprio(1);
    mm(acc[1], af, bv2);
    __builtin_amdgcn_s_setprio(0);
    WAITV6();            // drain (t,A1)
    SBAR();
    // ph2: quadrant (1,1) — reads A1 (reuses bv2)
    ldA(af2, 1, cb);
    stage(t + 1, 1);
    SBAR();
    __builtin_amdgcn_s_setprio(1);
    mm(acc[2], af2, bv2);
    __builtin_amdgcn_s_setprio(0);
    SBAR();
    // ph3: quadrant (1,0) — re-reads B0 (no new data, no stage)
    ldB(bv, 0, cb);
    SBAR();
    __builtin_amdgcn_s_setprio(1);
    mm(acc[3], af2, bv);
    __builtin_amdgcn_s_setprio(0);
    WAITV4();            // drain (t+1,A0)+(t+1,B0)
    SBAR();
  }

  // ---- epilogue (registers only) ----
  const int coll = lane & 15;
  const int rg = (lane >> 4) * 4;
  if (n0 >= 8192) {
#pragma unroll
    for (int q = 0; q < 4; ++q) {
      const int qm = (q >= 2);
      const int qn = (q == 1 || q == 2);
#pragma unroll
      for (int f = 0; f < 4; ++f)
#pragma unroll
        for (int r = 0; r < 4; ++r) {
          const int row = m0 + qm * 128 + wm * 64 + f * 16 + rg + r;
#pragma unroll
          for (int g = 0; g < 2; ++g) {
            const int gcol = (n0 - 8192) + qn * 128 + wn * 32 + g * 16 + coll;
            gvec[(size_t)row * 1024 + gcol] = acc[q][f][g][r];
          }
        }
    }
  } else {
    const int kidx = n0 >> 10;
    const int ebase = (n0 & 1023) + wn * 32 + coll;
#pragma unroll
    for (int qm = 0; qm < 2; ++qm) {
      f32x4 (*acA)[2] = acc[qm ? 3 : 0];  // qn=0
      f32x4 (*acB)[2] = acc[qm ? 2 : 1];  // qn=1
#pragma unroll
      for (int f = 0; f < 4; ++f)
#pragma unroll
        for (int r = 0; r < 4; ++r) {
          const int row = m0 + qm * 128 + wm * 64 + f * 16 + rg + r;
          const float* hr = hb + (size_t)row * 1024 + ebase;
          float tmp = acA[f][0][r] * hr[0] + acA[f][1][r] * hr[16] +
                      acB[f][0][r] * hr[128] + acB[f][1][r] * hr[144];
#pragma unroll
          for (int s = 1; s < 16; s <<= 1) tmp += __shfl_xor(tmp, s);
          if (coll == 0) atomicAdd(&x[row * 8 + kidx], tmp);
        }
    }
  }
}

// ---- per-batch: S = sum tanh(x), vec = S*(gvec+bc), softmax, out/attn ----
__global__ __launch_bounds__(256) void finalize_k(
    const float* __restrict__ xk, const float* __restrict__ gvec,
    const float* __restrict__ bc, const float* __restrict__ ha,
    float* __restrict__ out, float* __restrict__ attn) {
  int b = blockIdx.x;
  int tid = threadIdx.x;
  float S = 0.f;
#pragma unroll
  for (int k = 0; k < 8; ++k) S += tanhf(xk[b * 8 + k]);
  float v[4];
  float mx = -3.4e38f;
#pragma unroll
  for (int s = 0; s < 4; ++s) {
    int d = tid + s * 256;
    v[s] = S * (gvec[(size_t)b * 1024 + d] + bc[d]);
    mx = fmaxf(mx, v[s]);
  }
  __shared__ float red[8];
#pragma unroll
  for (int off = 32; off >= 1; off >>= 1) mx = fmaxf(mx, __shfl_xor(mx, off));
  int lane = tid & 63, w = tid >> 6;
  if (lane == 0) red[w] = mx;
  __syncthreads();
  float m = fmaxf(fmaxf(red[0], red[1]), fmaxf(red[2], red[3]));
  float e[4], sum = 0.f;
#pragma unroll
  for (int s = 0; s < 4; ++s) { e[s] = __expf(v[s] - m); sum += e[s]; }
#pragma unroll
  for (int off = 32; off >= 1; off >>= 1) sum += __shfl_xor(sum, off);
  if (lane == 0) red[4 + w] = sum;
  __syncthreads();
  float inv = 1.f / (red[4] + red[5] + red[6] + red[7]);
#pragma unroll
  for (int s = 0; s < 4; ++s) {
    int d = tid + s * 256;
    float a = e[s] * inv;
    attn[(size_t)b * 1024 + d] = a;
    float h = ha[(size_t)b * 1024 + d];
    out[(size_t)b * 1024 + d] = fmaf(a, h, h);
  }
}

extern "C" void kernel_launch(void* const* d_in, const int* in_sizes, int n_in,
                              void* d_out, int out_size, void* d_ws, size_t ws_size,
                              hipStream_t stream) {
  const float* l_hidden = (const float*)d_in[0];
  const float* m_hidden = (const float*)d_in[1];
  const float* G_l_m = (const float*)d_in[2];
  const float* G_m_l = (const float*)d_in[3];
  const float* l_fc1_w = (const float*)d_in[4];
  const float* l_fc1_b = (const float*)d_in[5];
  const float* l_fc2_w = (const float*)d_in[6];
  const float* l_fc2_b = (const float*)d_in[7];
  const float* m_fc1_w = (const float*)d_in[8];
  const float* m_fc1_b = (const float*)d_in[9];
  const float* m_fc2_w = (const float*)d_in[10];
  const float* m_fc2_b = (const float*)d_in[11];
  float* out = (float*)d_out;

  char* ws = (char*)d_ws;
  unsigned short* Ahi = (unsigned short*)(ws);                    // 16 MB
  unsigned short* Alo = (unsigned short*)(ws + 16777216);         // 16 MB
  unsigned short* Bhi = (unsigned short*)(ws + 33554432);         // 18 MB (9216x1024)
  unsigned short* Blo = (unsigned short*)(ws + 52428800);         // 18 MB
  float* gvec = (float*)(ws + 71303168);                          // 32 MB
  float* x = (float*)(ws + 104857600);                            // 512 KB (2 dirs)
  float* bc = (float*)(ws + 105381888);                           // 4 KB

  hipMemsetAsync(x, 0, 2 * NB * 8 * sizeof(float), stream);

  const size_t BD = (size_t)NB * DD;
  dim3 gemmGrid(1152);

  // direction l
  split_cast_k<<<(int)(BD / 4 / 256), 256, 0, stream>>>(l_hidden, Ahi, Alo, (int)(BD / 4));
  transpose_split_k<<<dim3(256, 32), 256, 0, stream>>>(G_l_m, Bhi, Blo);
  wct_k<<<1024, 256, 0, stream>>>(l_fc1_w, l_fc1_b, l_fc2_w, l_fc2_b, 256, Bhi, Blo, bc);
  gemm_k<<<gemmGrid, 512, 0, stream>>>(Ahi, Alo, Bhi, Blo, m_hidden, gvec, x);
  finalize_k<<<NB, 256, 0, stream>>>(x, gvec, bc, l_hidden, out, out + 2 * BD);

  // direction m
  split_cast_k<<<(int)(BD / 4 / 256), 256, 0, stream>>>(m_hidden, Ahi, Alo, (int)(BD / 4));
  transpose_split_k<<<dim3(256, 32), 256, 0, stream>>>(G_m_l, Bhi, Blo);
  wct_k<<<1024, 256, 0, stream>>>(m_fc1_w, m_fc1_b, m_fc2_w, m_fc2_b, 128, Bhi, Blo, bc);
  gemm_k<<<gemmGrid, 512, 0, stream>>>(Ahi, Alo, Bhi, Blo, l_hidden, gvec, x + NB * 8);
  finalize_k<<<NB, 256, 0, stream>>>(x + NB * 8, gvec, bc, m_hidden, out + BD, out + 3 * BD);
}